// Round 1
// 575.325 us; speedup vs baseline: 1.1331x; 1.1331x over previous
//
#include <hip/hip_runtime.h>
#include <stdint.h>

// Bahdanau additive attention. S=2048, B=32, H=1024.
// context[b,h] = sum_s softmax_s(mask(v . tanh(W1 hs + b1 + W2 h + b2))) * hs
//
// Fast path (needs ~138.4 MB workspace):
//  0) convert_f16: hs,W1 -> f16 copies in ws
//  1) t2_kernel:   t2[b,n] = b1[n]+b2[n]+hidden.W2row
//  2) gemm_energy_8p: 256x256x(BK=64) f16 MFMA, 8 waves (2Mx4N), 8-phase
//     counted-vmcnt schedule (T3+T4+T5 per m201 template): per K-tile 4 phases
//     of {ds_read subtile | stage 1 half-tile -> bar -> lgkm0 -> setprio ->
//     16 MFMA -> bar}, vmcnt(4) once per K-tile (never 0 in main loop).
//     XOR-swizzled LDS (0 bank conflicts, carried from r4), global_load_lds 16B,
//     bijective XCD swizzle (1024 blocks % 8 == 0),
//     fused tanh+dot(v) epilogue -> epart[p][b][s], p = nb*4+wc (16 partials).
//  3) softmax16t: 32 blocks x 1024 thr, coalesced slice reduction, attn[b][s]
//  4) context_f16t: attn chunk preloaded to LDS, unrolled hs row loads
//  5) ctx_reduce32
// Fallback path = round-2 kernels (3.4 MB ws), known-passing, own layouts.

#define SS 2048
#define BB 32
#define HH 1024
#define MM (SS*BB)   // 65536

typedef _Float16 f16;
typedef __attribute__((ext_vector_type(8))) _Float16 f16x8;
typedef __attribute__((ext_vector_type(4))) _Float16 f16x4;
typedef __attribute__((ext_vector_type(4))) float   floatx4;

__device__ __forceinline__ float tanh_fast(float x) {
  float e = __expf(2.0f * x);
  return 1.0f - 2.0f / (e + 1.0f);
}

// async global->LDS, 16B/lane. LDS dest = wave-uniform base + lane*16.
__device__ __forceinline__ void gload16(void* lds_base, const void* gptr) {
  __builtin_amdgcn_global_load_lds(
      (const __attribute__((address_space(1))) uint32_t*)(uintptr_t)gptr,
      (__attribute__((address_space(3))) uint32_t*)(uint32_t)(uintptr_t)lds_base,
      16, 0, 0);
}

#define BAR()   __builtin_amdgcn_s_barrier()
#define LGKM0() asm volatile("s_waitcnt lgkmcnt(0)" ::: "memory")
#define VMC4()  asm volatile("s_waitcnt vmcnt(4)" ::: "memory")
#define VMC0()  asm volatile("s_waitcnt vmcnt(0)" ::: "memory")

// ---------------- convert: fp32 -> f16 for hs and W1 ----------------
__global__ __launch_bounds__(256) void convert_f16(
    const float* __restrict__ hs, const float* __restrict__ W1,
    f16* __restrict__ hsf, f16* __restrict__ W1f)
{
  const size_t NH = (size_t)MM * HH;   // 64M
  size_t base = ((size_t)blockIdx.x * 256 + threadIdx.x) * 8;
  if (base < NH) {
    floatx4 a = *(const floatx4*)&hs[base];
    floatx4 b = *(const floatx4*)&hs[base + 4];
    f16x8 o = {(f16)a.x,(f16)a.y,(f16)a.z,(f16)a.w,(f16)b.x,(f16)b.y,(f16)b.z,(f16)b.w};
    *(f16x8*)&hsf[base] = o;
  } else {
    size_t wb = base - NH;
    if (wb < (size_t)HH * HH) {
      floatx4 a = *(const floatx4*)&W1[wb];
      floatx4 b = *(const floatx4*)&W1[wb + 4];
      f16x8 o = {(f16)a.x,(f16)a.y,(f16)a.z,(f16)a.w,(f16)b.x,(f16)b.y,(f16)b.z,(f16)b.w};
      *(f16x8*)&W1f[wb] = o;
    }
  }
}

// ---------------- t2 = hidden @ W2^T + b1 + b2 ----------------
__global__ __launch_bounds__(256) void t2_kernel(
    const float* __restrict__ hidden, const float* __restrict__ W2,
    const float* __restrict__ b1, const float* __restrict__ b2,
    float* __restrict__ t2)
{
  const int gw   = blockIdx.x * 4 + (threadIdx.x >> 6);
  const int n    = gw >> 5;
  const int b    = gw & 31;
  const int lane = threadIdx.x & 63;
  float acc = 0.f;
#pragma unroll
  for (int q = 0; q < 4; ++q) {
    floatx4 hv = *(const floatx4*)&hidden[b * HH + q * 256 + lane * 4];
    floatx4 wv = *(const floatx4*)&W2[(size_t)n * HH + q * 256 + lane * 4];
    acc += hv.x * wv.x + hv.y * wv.y + hv.z * wv.z + hv.w * wv.w;
  }
#pragma unroll
  for (int off = 1; off < 64; off <<= 1) acc += __shfl_xor(acc, off);
  if (lane == 0) t2[b * HH + n] = acc + b1[n] + b2[n];
}

// ---------------- 256x256 8-phase f16 MFMA GEMM + tanh + dot(v) ----------------
// A = hsf [65536 x 1024], B = W1f [1024 x 1024] (both K-major).
// 8 waves: wr = w>>2 (2 in M, 128 rows/wave), wc = w&3 (4 in N, 64 cols/wave).
// LDS: 2 dbuf x 2 halves x 128x64 f16 for A and B = 128 KiB.
// Per K-tile t (buf=t&1): p1 Q(0,0) reads A-qm0+B-qn0, stages A1(t+1);
//   p2 Q(0,1) reads B-qn1, stages B1(t+1); p3 Q(1,1) reads A-qm1, stages B0(t+2);
//   p4 Q(1,0) (regs only), stages A0(t+2), vmcnt(4).
// Overwrite-safety: each stage targets a region whose last ds_read finished a
// full barrier earlier (A halves last read p3, B halves last read p2).
// vmcnt(4) at p4(t) forces tile t+1 fully landed (only the 2 halves of t+2
// issued at p3/p4 may remain in flight).
__global__ __launch_bounds__(512, 2) void gemm_energy_8p(
    const f16* __restrict__ hsf, const f16* __restrict__ W1f,
    const float* __restrict__ t2, const float* __restrict__ v,
    float* __restrict__ epart)
{
  __shared__ __align__(16) f16 Asm[2][2][128 * 64];
  __shared__ __align__(16) f16 Bsm[2][2][128 * 64];

  const int tid  = threadIdx.x;
  const int lane = tid & 63;
  const int w    = tid >> 6;      // 0..7
  const int quad = lane >> 4;
  const int l15  = lane & 15;
  const int wr   = w >> 2;        // 0..1 : M
  const int wc   = w & 3;         // 0..3 : N

  // bijective XCD swizzle: 1024 blocks, 4 nb of one mtile consecutive per XCD
  const int l  = blockIdx.x;
  const int x  = l & 7;
  const int j_ = l >> 3;
  const int nb = j_ & 3;
  const int mt = (j_ >> 2) * 8 + x;
  const int mB = mt * 256;
  const int nB = nb * 256;

  const int srow = w * 8 + (lane >> 3);   // 0..63 within one 64-row q-group
  const int sc0  = lane & 7;

  auto stA = [&](int buf, int half, int kt) {
#pragma unroll
    for (int q = 0; q < 2; ++q) {
      const int r  = q * 64 + srow;
      const int cb = sc0 ^ (r & 7);          // pre-swizzled global source
      gload16(&Asm[buf][half][(q * 64 + w * 8) * 64],
              &hsf[(size_t)(mB + half * 128 + r) * HH + kt + cb * 8]);
    }
  };
  auto stB = [&](int buf, int half, int kt) {
#pragma unroll
    for (int q = 0; q < 2; ++q) {
      const int r  = q * 64 + srow;
      const int cb = sc0 ^ (r & 7);
      gload16(&Bsm[buf][half][(q * 64 + w * 8) * 64],
              &W1f[(size_t)(nB + half * 128 + r) * HH + kt + cb * 8]);
    }
  };

  floatx4 acc[8][4];
#pragma unroll
  for (int i = 0; i < 8; ++i)
#pragma unroll
    for (int j = 0; j < 4; ++j) acc[i][j] = (floatx4){0.f, 0.f, 0.f, 0.f};

  // prologue: tile0 full + tile1 {B0, A0}; vmcnt(4) -> tile0 landed
  stB(0, 0, 0); stA(0, 0, 0); stA(0, 1, 0); stB(0, 1, 0);
  stB(1, 0, 64); stA(1, 0, 64);
  VMC4();
  BAR();

  f16x8 aF[2][4], b0F[2][2], b1F[2][2];
  const int bhalf  = wc >> 1;
  const int brbase = (wc & 1) * 64;

#pragma unroll 2
  for (int t = 0; t < 16; ++t) {
    const int buf = t & 1, nbuf = buf ^ 1;
    const int kt1 = (t + 1) * 64, kt2 = (t + 2) * 64;

    // ---------- phase 1 : Q(0,0) — 12 ds_read ----------
#pragma unroll
    for (int ks = 0; ks < 2; ++ks) {
#pragma unroll
      for (int i = 0; i < 4; ++i) {
        const int rl = i * 16 + l15;
        const int cb = (ks * 4 + quad) ^ (rl & 7);
        aF[ks][i] = *(const f16x8*)&Asm[buf][wr][(rl * 8 + cb) * 8];
      }
#pragma unroll
      for (int j = 0; j < 2; ++j) {
        const int rl = brbase + j * 16 + l15;
        const int cb = (ks * 4 + quad) ^ (rl & 7);
        b0F[ks][j] = *(const f16x8*)&Bsm[buf][bhalf][(rl * 8 + cb) * 8];
      }
    }
    if (t < 15) stA(nbuf, 1, kt1);
    BAR(); LGKM0();
    __builtin_amdgcn_s_setprio(1);
#pragma unroll
    for (int ks = 0; ks < 2; ++ks)
#pragma unroll
      for (int i = 0; i < 4; ++i)
#pragma unroll
        for (int j = 0; j < 2; ++j)
          acc[i][j] = __builtin_amdgcn_mfma_f32_16x16x32_f16(aF[ks][i], b0F[ks][j], acc[i][j], 0, 0, 0);
    __builtin_amdgcn_s_setprio(0);
    BAR();

    // ---------- phase 2 : Q(0,1) — 4 ds_read ----------
#pragma unroll
    for (int ks = 0; ks < 2; ++ks)
#pragma unroll
      for (int j = 0; j < 2; ++j) {
        const int rl = brbase + (j + 2) * 16 + l15;
        const int cb = (ks * 4 + quad) ^ (rl & 7);
        b1F[ks][j] = *(const f16x8*)&Bsm[buf][bhalf][(rl * 8 + cb) * 8];
      }
    if (t < 15) stB(nbuf, 1, kt1);
    BAR(); LGKM0();
    __builtin_amdgcn_s_setprio(1);
#pragma unroll
    for (int ks = 0; ks < 2; ++ks)
#pragma unroll
      for (int i = 0; i < 4; ++i)
#pragma unroll
        for (int j = 0; j < 2; ++j)
          acc[i][2 + j] = __builtin_amdgcn_mfma_f32_16x16x32_f16(aF[ks][i], b1F[ks][j], acc[i][2 + j], 0, 0, 0);
    __builtin_amdgcn_s_setprio(0);
    BAR();

    // ---------- phase 3 : Q(1,1) — 8 ds_read ----------
#pragma unroll
    for (int ks = 0; ks < 2; ++ks)
#pragma unroll
      for (int i = 0; i < 4; ++i) {
        const int rl = 64 + i * 16 + l15;
        const int cb = (ks * 4 + quad) ^ (rl & 7);
        aF[ks][i] = *(const f16x8*)&Asm[buf][wr][(rl * 8 + cb) * 8];
      }
    if (t < 14) stB(buf, 0, kt2);
    BAR(); LGKM0();
    __builtin_amdgcn_s_setprio(1);
#pragma unroll
    for (int ks = 0; ks < 2; ++ks)
#pragma unroll
      for (int i = 0; i < 4; ++i)
#pragma unroll
        for (int j = 0; j < 2; ++j)
          acc[4 + i][2 + j] = __builtin_amdgcn_mfma_f32_16x16x32_f16(aF[ks][i], b1F[ks][j], acc[4 + i][2 + j], 0, 0, 0);
    __builtin_amdgcn_s_setprio(0);
    BAR();

    // ---------- phase 4 : Q(1,0) — regs only ----------
    if (t < 14) stA(buf, 0, kt2);
    BAR();
    __builtin_amdgcn_s_setprio(1);
#pragma unroll
    for (int ks = 0; ks < 2; ++ks)
#pragma unroll
      for (int i = 0; i < 4; ++i)
#pragma unroll
        for (int j = 0; j < 2; ++j)
          acc[4 + i][j] = __builtin_amdgcn_mfma_f32_16x16x32_f16(aF[ks][i], b0F[ks][j], acc[4 + i][j], 0, 0, 0);
    __builtin_amdgcn_s_setprio(0);
    if (t < 14) { VMC4(); } else { VMC0(); }
    BAR();
  }

  // epilogue: C/D layout col=lane&15, row=quad*4+reg.
  // write transposed: epart[p][b][s], p = nb*4+wc
  float vv[4];
#pragma unroll
  for (int j = 0; j < 4; ++j) vv[j] = v[nB + wc * 64 + j * 16 + l15];
#pragma unroll
  for (int i = 0; i < 8; ++i) {
#pragma unroll
    for (int reg = 0; reg < 4; ++reg) {
      const int m = mB + wr * 128 + i * 16 + quad * 4 + reg;
      const int b = m & (BB - 1);
      const int s = m >> 5;
      float rs = 0.f;
#pragma unroll
      for (int j = 0; j < 4; ++j) {
        const int n = nB + wc * 64 + j * 16 + l15;
        rs += tanh_fast(acc[i][j][reg] + t2[b * HH + n]) * vv[j];
      }
      rs += __shfl_xor(rs, 1);
      rs += __shfl_xor(rs, 2);
      rs += __shfl_xor(rs, 4);
      rs += __shfl_xor(rs, 8);
      if (l15 == 0) epart[(size_t)(nb * 4 + wc) * MM + b * SS + s] = rs;
    }
  }
}

// ---------------- softmax over s per batch column ----------------
// epart[p][b][s] -> coalesced in s. 32 blocks x 1024 threads, 2 s per thread.
// attn written as attn[b][s].
__global__ __launch_bounds__(1024) void softmax16t(
    const float* __restrict__ epart, const int* __restrict__ masks,
    float* __restrict__ attn)
{
  const int b = blockIdx.x;
  const int tid = threadIdx.x;   // 0..1023
  __shared__ float redm[16], reds[16];
  float em[2];
  float lmax = -3e38f;
#pragma unroll
  for (int it = 0; it < 2; ++it) {
    const int s = it * 1024 + tid;
    float e = 0.f;
#pragma unroll
    for (int p = 0; p < 16; ++p) e += epart[(size_t)p * MM + b * SS + s];
    if (masks[s * BB + b] == 0) e = -1e10f;
    em[it] = e;
    lmax = fmaxf(lmax, e);
  }
#pragma unroll
  for (int off = 1; off < 64; off <<= 1) lmax = fmaxf(lmax, __shfl_xor(lmax, off));
  if ((tid & 63) == 0) redm[tid >> 6] = lmax;
  __syncthreads();
#pragma unroll
  for (int i = 0; i < 16; ++i) lmax = fmaxf(lmax, redm[i]);
  float lsum = 0.f;
#pragma unroll
  for (int it = 0; it < 2; ++it) { em[it] = __expf(em[it] - lmax); lsum += em[it]; }
#pragma unroll
  for (int off = 1; off < 64; off <<= 1) lsum += __shfl_xor(lsum, off);
  if ((tid & 63) == 0) reds[tid >> 6] = lsum;
  __syncthreads();
  float tsum = 0.f;
#pragma unroll
  for (int i = 0; i < 16; ++i) tsum += reds[i];
  const float inv = 1.0f / tsum;
#pragma unroll
  for (int it = 0; it < 2; ++it) attn[b * SS + it * 1024 + tid] = em[it] * inv;
}

// ---------------- context partials from f16 hs ----------------
__global__ __launch_bounds__(256) void context_f16t(
    const f16* __restrict__ hsf, const float* __restrict__ attn,
    float* __restrict__ ctxp)
{
  const int b  = blockIdx.x;
  const int sc = blockIdx.y;
  const int tid = threadIdx.x;
  __shared__ float sat[64];
  if (tid < 64) sat[tid] = attn[b * SS + sc * 64 + tid];
  __syncthreads();
  floatx4 acc = {0.f, 0.f, 0.f, 0.f};
#pragma unroll 4
  for (int s = 0; s < 64; ++s) {
    const float a = sat[s];
    if (a != 0.f) {   // block-uniform branch; masked rows skip the load
      f16x4 h = *(const f16x4*)&hsf[(size_t)((sc * 64 + s) * BB + b) * HH + tid * 4];
      acc.x += a * (float)h[0];
      acc.y += a * (float)h[1];
      acc.z += a * (float)h[2];
      acc.w += a * (float)h[3];
    }
  }
  *(floatx4*)&ctxp[(size_t)(sc * BB + b) * HH + tid * 4] = acc;
}

__global__ __launch_bounds__(256) void ctx_reduce32(
    const float* __restrict__ ctxp, float* __restrict__ out)
{
  const int i = blockIdx.x * 256 + threadIdx.x;
  float s = 0.f;
#pragma unroll
  for (int sc = 0; sc < 32; ++sc) s += ctxp[(size_t)sc * (BB * HH) + i];
  out[i] = s;
}

// ================= fallback path (round-2, known-passing, 3.4 MB ws) =================
__global__ __launch_bounds__(256) void gemm_energy_fb(
    const float* __restrict__ hs, const float* __restrict__ W1,
    const float* __restrict__ t2, const float* __restrict__ v,
    float* __restrict__ epart)
{
  const int tid = threadIdx.x;
  const int nb  = blockIdx.x;
  const int mB  = blockIdx.y * 128;
  __shared__ __align__(16) f16 Asm[128][72];
  __shared__ __align__(16) f16 Bsm[128][72];
  const int lane = tid & 63;
  const int w    = tid >> 6;
  const int quad = lane >> 4;
  const int l15  = lane & 15;
  floatx4 acc[2][8];
#pragma unroll
  for (int i = 0; i < 2; ++i)
#pragma unroll
    for (int j = 0; j < 8; ++j) acc[i][j] = (floatx4){0.f, 0.f, 0.f, 0.f};
  const int srow = tid >> 4;
  const int scol = (tid & 15) * 4;
  const float* Abase = hs + (size_t)(mB + srow) * HH + scol;
  const float* Bbase = W1 + (size_t)(nb * 128 + srow) * HH + scol;
  for (int kt = 0; kt < HH; kt += 64) {
#pragma unroll
    for (int p = 0; p < 8; ++p) {
      floatx4 fa = *(const floatx4*)(Abase + (size_t)(p * 16) * HH + kt);
      floatx4 fb = *(const floatx4*)(Bbase + (size_t)(p * 16) * HH + kt);
      f16x4 ha = {(f16)fa.x, (f16)fa.y, (f16)fa.z, (f16)fa.w};
      f16x4 hb = {(f16)fb.x, (f16)fb.y, (f16)fb.z, (f16)fb.w};
      *(f16x4*)&Asm[p * 16 + srow][scol] = ha;
      *(f16x4*)&Bsm[p * 16 + srow][scol] = hb;
    }
    __syncthreads();
#pragma unroll
    for (int ks = 0; ks < 2; ++ks) {
      f16x8 af[2], bfr[8];
#pragma unroll
      for (int i = 0; i < 2; ++i)
        af[i] = *(const f16x8*)&Asm[w * 32 + i * 16 + l15][ks * 32 + quad * 8];
#pragma unroll
      for (int j = 0; j < 8; ++j)
        bfr[j] = *(const f16x8*)&Bsm[j * 16 + l15][ks * 32 + quad * 8];
#pragma unroll
      for (int i = 0; i < 2; ++i)
#pragma unroll
        for (int j = 0; j < 8; ++j)
          acc[i][j] = __builtin_amdgcn_mfma_f32_16x16x32_f16(af[i], bfr[j], acc[i][j], 0, 0, 0);
    }
    __syncthreads();
  }
  const int nB = nb * 128;
#pragma unroll
  for (int i = 0; i < 2; ++i) {
#pragma unroll
    for (int reg = 0; reg < 4; ++reg) {
      const int m = mB + w * 32 + i * 16 + quad * 4 + reg;
      const int b = m & (BB - 1);
      float rs = 0.f;
#pragma unroll
      for (int j = 0; j < 8; ++j) {
        const int n = nB + j * 16 + l15;
        rs += tanh_fast(acc[i][j][reg] + t2[b * HH + n]) * v[n];
      }
      rs += __shfl_xor(rs, 1);
      rs += __shfl_xor(rs, 2);
      rs += __shfl_xor(rs, 4);
      rs += __shfl_xor(rs, 8);
      if (l15 == 0) epart[(size_t)nb * MM + m] = rs;
    }
  }
}

__global__ __launch_bounds__(256) void softmax8(
    const float* __restrict__ epart, const int* __restrict__ masks,
    float* __restrict__ attn)
{
  const int b = blockIdx.x;
  const int tid = threadIdx.x;
  __shared__ float redm[4], reds[4];
  float em[8];
  float lmax = -3e38f;
#pragma unroll
  for (int it = 0; it < 8; ++it) {
    const int s = it * 256 + tid;
    float e = 0.f;
#pragma unroll
    for (int p = 0; p < 8; ++p) e += epart[(size_t)p * MM + s * BB + b];
    if (masks[s * BB + b] == 0) e = -1e10f;
    em[it] = e;
    lmax = fmaxf(lmax, e);
  }
#pragma unroll
  for (int off = 1; off < 64; off <<= 1) lmax = fmaxf(lmax, __shfl_xor(lmax, off));
  if ((tid & 63) == 0) redm[tid >> 6] = lmax;
  __syncthreads();
  lmax = fmaxf(fmaxf(redm[0], redm[1]), fmaxf(redm[2], redm[3]));
  float lsum = 0.f;
#pragma unroll
  for (int it = 0; it < 8; ++it) { em[it] = __expf(em[it] - lmax); lsum += em[it]; }
#pragma unroll
  for (int off = 1; off < 64; off <<= 1) lsum += __shfl_xor(lsum, off);
  if ((tid & 63) == 0) reds[tid >> 6] = lsum;
  __syncthreads();
  const float inv = 1.0f / (reds[0] + reds[1] + reds[2] + reds[3]);
#pragma unroll
  for (int it = 0; it < 8; ++it) attn[(it * 256 + tid) * BB + b] = em[it] * inv;
}

__global__ __launch_bounds__(256) void context_fb(
    const float* __restrict__ hs, const float* __restrict__ attn,
    float* __restrict__ ctxp)
{
  const int b  = blockIdx.x;
  const int sc = blockIdx.y;
  const int tid = threadIdx.x;
  floatx4 acc = {0.f, 0.f, 0.f, 0.f};
  for (int s = sc * 256; s < sc * 256 + 256; ++s) {
    const float a = attn[s * BB + b];
    if (a != 0.f) {
      floatx4 h = *(const floatx4*)&hs[(size_t)(s * BB + b) * HH + tid * 4];
      acc.x += a * h.x; acc.y += a * h.y; acc.z += a * h.z; acc.w += a * h.w;
    }
  }
  *(floatx4*)&ctxp[(size_t)(sc * BB + b) * HH + tid * 4] = acc;
}

__global__ __launch_bounds__(256) void ctx_reduce8(
    const float* __restrict__ ctxp, float* __restrict__ out)
{
  const int i = blockIdx.x * 256 + threadIdx.x;
  float s = 0.f;
#pragma unroll
  for (int sc = 0; sc < 8; ++sc) s += ctxp[(size_t)sc * (BB * HH) + i];
  out[i] = s;
}

extern "C" void kernel_launch(void* const* d_in, const int* in_sizes, int n_in,
                              void* d_out, int out_size, void* d_ws, size_t ws_size,
                              hipStream_t stream) {
  const float* hidden = (const float*)d_in[0];  // (1,B,H)
  const float* hs     = (const float*)d_in[1];  // (S,B,H)
  const int*   masks  = (const int*)d_in[2];    // (S,B)
  const float* W1     = (const float*)d_in[3];  // (H,H)
  const float* b1     = (const float*)d_in[4];  // (H,)
  const float* W2     = (const float*)d_in[5];  // (H,H)
  const float* b2     = (const float*)d_in[6];  // (H,)
  const float* v      = (const float*)d_in[7];  // (H,)
  float* out = (float*)d_out;                   // (1,B,H)

  const size_t hsf_b   = (size_t)MM * HH * 2;    // 128 MB
  const size_t w1f_b   = (size_t)HH * HH * 2;    // 2 MB
  const size_t epart_b = (size_t)16 * MM * 4;    // 4 MB
  const size_t attn_b  = (size_t)MM * 4;         // 256 KB
  const size_t t2_b    = (size_t)BB * HH * 4;    // 128 KB
  const size_t ctxp_b  = (size_t)32 * BB * HH * 4; // 4 MB
  const size_t need = hsf_b + w1f_b + epart_b + attn_b + t2_b + ctxp_b;

  if (ws_size >= need) {
    char* p = (char*)d_ws;
    f16*   hsf   = (f16*)p;              p += hsf_b;
    f16*   W1f   = (f16*)p;              p += w1f_b;
    float* epart = (float*)p;            p += epart_b;
    float* attn  = (float*)p;            p += attn_b;
    float* t2    = (float*)p;            p += t2_b;
    float* ctxp  = (float*)p;

    convert_f16<<<dim3(33280), 256, 0, stream>>>(hs, W1, hsf, W1f);
    t2_kernel<<<dim3(BB * HH / 4), 256, 0, stream>>>(hidden, W2, b1, b2, t2);
    gemm_energy_8p<<<dim3(1024), 512, 0, stream>>>(hsf, W1f, t2, v, epart);
    softmax16t<<<dim3(BB), 1024, 0, stream>>>(epart, masks, attn);
    context_f16t<<<dim3(BB, 32), 256, 0, stream>>>(hsf, attn, ctxp);
    ctx_reduce32<<<dim3(BB * HH / 256), 256, 0, stream>>>(ctxp, out);
  } else {
    float* epart = (float*)d_ws;          // 8*MM
    float* attn  = epart + 8 * MM;        // MM
    float* t2    = attn + MM;             // BB*HH
    float* ctxp  = t2 + BB * HH;          // 8*BB*HH

    t2_kernel<<<dim3(BB * HH / 4), 256, 0, stream>>>(hidden, W2, b1, b2, t2);
    gemm_energy_fb<<<dim3(8, MM / 128), 256, 0, stream>>>(hs, W1, t2, v, epart);
    softmax8<<<dim3(BB), 256, 0, stream>>>(epart, masks, attn);
    context_fb<<<dim3(BB, 8), 256, 0, stream>>>(hs, attn, ctxp);
    ctx_reduce8<<<dim3(BB * HH / 256), 256, 0, stream>>>(ctxp, out);
  }
}

// Round 2
// 569.538 us; speedup vs baseline: 1.1446x; 1.0102x over previous
//
#include <hip/hip_runtime.h>
#include <stdint.h>

// Bahdanau additive attention. S=2048, B=32, H=1024.
// context[b,h] = sum_s softmax_s(mask(v . tanh(W1 hs + b1 + W2 h + b2))) * hs
//
// Fast path (needs ~138.4 MB workspace):
//  0) prep: fused {hs,W1 -> f16 (coalesced float4 pairs)} + {t2[b,n] =
//     b1[n]+b2[n]+hidden.W2row} in one launch (block ranges).
//  2) gemm_energy_8p: 256x256x(BK=64) f16 MFMA, 8 waves (2Mx4N), 4 phases/
//     K-tile, ONE barrier per phase (overwrite-safety bounded by phase-END
//     barriers only — see hazard notes inline), counted vmcnt(4) once per
//     tile (never 0 in main loop), XOR-swizzled LDS (0 conflicts),
//     global_load_lds 16B, bijective XCD swizzle. Epilogue: t2 slice staged
//     to LDS (reuses Asm), tanh+dot(v), DPP butterfly 16-lane reduction
//     (no ds_bpermute), writes epart[p][b][s], p = nb*4+wc (16 partials).
//  3) softmax16t: 32 blocks x 1024 thr, coalesced slice reduction, attn[b][s]
//  4) context_f16t: attn chunk preloaded to LDS, unrolled hs row loads
//  5) ctx_reduce32
// Fallback path = round-2 kernels (3.4 MB ws), known-passing, own layouts.

#define SS 2048
#define BB 32
#define HH 1024
#define MM (SS*BB)   // 65536

typedef _Float16 f16;
typedef __attribute__((ext_vector_type(8))) _Float16 f16x8;
typedef __attribute__((ext_vector_type(4))) _Float16 f16x4;
typedef __attribute__((ext_vector_type(4))) float   floatx4;

__device__ __forceinline__ float tanh_fast(float x) {
  float e = __expf(2.0f * x);
  return 1.0f - 2.0f / (e + 1.0f);
}

// async global->LDS, 16B/lane. LDS dest = wave-uniform base + lane*16.
__device__ __forceinline__ void gload16(void* lds_base, const void* gptr) {
  __builtin_amdgcn_global_load_lds(
      (const __attribute__((address_space(1))) uint32_t*)(uintptr_t)gptr,
      (__attribute__((address_space(3))) uint32_t*)(uint32_t)(uintptr_t)lds_base,
      16, 0, 0);
}

#define BAR()   __builtin_amdgcn_s_barrier()
#define VMC4()  asm volatile("s_waitcnt vmcnt(4)" ::: "memory")
#define VMC0()  asm volatile("s_waitcnt vmcnt(0)" ::: "memory")

// 16-lane (same lane>>4 group) butterfly sum via DPP: xor1, xor2 (quad_perm),
// lane^7 (row_half_mirror), lane^15 (row_mirror). All pure VALU — no LDS pipe.
__device__ __forceinline__ float dpp_red16(float x) {
  int t;
  t = __builtin_amdgcn_update_dpp(0, __float_as_int(x), 0xB1, 0xF, 0xF, true);   // quad_perm [1,0,3,2] = xor1
  x += __int_as_float(t);
  t = __builtin_amdgcn_update_dpp(0, __float_as_int(x), 0x4E, 0xF, 0xF, true);   // quad_perm [2,3,0,1] = xor2
  x += __int_as_float(t);
  t = __builtin_amdgcn_update_dpp(0, __float_as_int(x), 0x141, 0xF, 0xF, true);  // row_half_mirror = xor7
  x += __int_as_float(t);
  t = __builtin_amdgcn_update_dpp(0, __float_as_int(x), 0x140, 0xF, 0xF, true);  // row_mirror = xor15
  x += __int_as_float(t);
  return x;
}

// ---------------- prep: fp32->f16 convert (hs, W1) + t2 ----------------
// blocks [0, 33280): convert 2048 consecutive floats of concat(hs, W1).
//   NH = 64Mi floats = blocks 0..32767 exactly; W1 = 1Mi = blocks 32768..33279.
//   Two coalesced float4 loads (+0, +1024 floats), two 8B f16x4 stores.
// blocks [33280, 41472): t2[b,n] = dot(hidden[b], W2[n]) + b1[n] + b2[n].
__global__ __launch_bounds__(256) void prep_kernel(
    const float* __restrict__ hs, const float* __restrict__ W1,
    const float* __restrict__ hidden, const float* __restrict__ W2,
    const float* __restrict__ b1, const float* __restrict__ b2,
    f16* __restrict__ hsf, f16* __restrict__ W1f, float* __restrict__ t2)
{
  const int bid = blockIdx.x;
  if (bid < 33280) {
    const size_t NH = (size_t)MM * HH;   // 64M floats
    size_t g0 = (size_t)bid * 2048 + threadIdx.x * 4;
    const float* src;
    f16* dst;
    if (g0 < NH) { src = hs; dst = hsf; }
    else         { src = W1 - NH; dst = W1f - NH; }  // offset fold
    floatx4 a = *(const floatx4*)&src[g0];
    floatx4 b = *(const floatx4*)&src[g0 + 1024];
    f16x4 oa = {(f16)a.x,(f16)a.y,(f16)a.z,(f16)a.w};
    f16x4 ob = {(f16)b.x,(f16)b.y,(f16)b.z,(f16)b.w};
    *(f16x4*)&dst[g0] = oa;
    *(f16x4*)&dst[g0 + 1024] = ob;
  } else {
    const int gw   = (bid - 33280) * 4 + (threadIdx.x >> 6);
    const int n    = gw >> 5;
    const int b    = gw & 31;
    const int lane = threadIdx.x & 63;
    float acc = 0.f;
#pragma unroll
    for (int q = 0; q < 4; ++q) {
      floatx4 hv = *(const floatx4*)&hidden[b * HH + q * 256 + lane * 4];
      floatx4 wv = *(const floatx4*)&W2[(size_t)n * HH + q * 256 + lane * 4];
      acc += hv.x * wv.x + hv.y * wv.y + hv.z * wv.z + hv.w * wv.w;
    }
#pragma unroll
    for (int off = 1; off < 64; off <<= 1) acc += __shfl_xor(acc, off);
    if (lane == 0) t2[b * HH + n] = acc + b1[n] + b2[n];
  }
}

// ---------------- 256x256 4-phase f16 MFMA GEMM + tanh + dot(v) ----------------
// A = hsf [65536 x 1024], B = W1f [1024 x 1024] (both K-major).
// 8 waves: wr = w>>2 (2 in M, 128 rows/wave), wc = w&3 (4 in N, 64 cols/wave).
// LDS: 2 dbuf x 2 halves x 128x64 f16 for A and B = 128 KiB.
// Per K-tile t (buf=t&1), ONE barrier per phase (at phase end):
//   p1 Q(0,0): reads A[buf][wr] rows 0-63 + B half rows lo, stages A1(t+1)
//   p2 Q(0,1): reads B half rows hi,                        stages B1(t+1)
//   p3 Q(1,1): reads A[buf][wr] rows 64-127,                stages B0(t+2)
//   p4 Q(1,0): regs only,                                   stages A0(t+2),
//              then vmcnt(4) (t<14; else vmcnt(0)) before the tile-end barrier.
// Overwrite-safety (all bounded by phase-END barriers):
//   stA(nbuf,1)@p1(t): A[nbuf][1] last read p3(t-1), done before p3-end BAR. OK
//   stB(nbuf,1)@p2(t): B[nbuf][1] last read p2(t-1).                        OK
//   stB(buf,0) @p3(t): B[buf][0]  last read p2(t),  done before p2-end BAR. OK
//   stA(buf,0) @p4(t): A[buf][0]  last read p3(t),  done before p3-end BAR. OK
// vmcnt(4)@p4(t) completes all 4 halves of tile t+1 (leaves t+2 half0s in
// flight); the tile-end barrier publishes them to all waves.
__global__ __launch_bounds__(512, 2) void gemm_energy_8p(
    const f16* __restrict__ hsf, const f16* __restrict__ W1f,
    const float* __restrict__ t2, const float* __restrict__ v,
    float* __restrict__ epart)
{
  __shared__ __align__(16) f16 Asm[2][2][128 * 64];
  __shared__ __align__(16) f16 Bsm[2][2][128 * 64];

  const int tid  = threadIdx.x;
  const int lane = tid & 63;
  const int w    = tid >> 6;      // 0..7
  const int quad = lane >> 4;
  const int l15  = lane & 15;
  const int wr   = w >> 2;        // 0..1 : M
  const int wc   = w & 3;         // 0..3 : N

  // bijective XCD swizzle: 1024 blocks, 4 nb of one mtile consecutive per XCD
  const int l  = blockIdx.x;
  const int x  = l & 7;
  const int j_ = l >> 3;
  const int nb = j_ & 3;
  const int mt = (j_ >> 2) * 8 + x;
  const int mB = mt * 256;
  const int nB = nb * 256;

  const int srow = w * 8 + (lane >> 3);   // 0..63 within one 64-row q-group
  const int sc0  = lane & 7;

  auto stA = [&](int buf, int half, int kt) {
#pragma unroll
    for (int q = 0; q < 2; ++q) {
      const int r  = q * 64 + srow;
      const int cb = sc0 ^ (r & 7);          // pre-swizzled global source
      gload16(&Asm[buf][half][(q * 64 + w * 8) * 64],
              &hsf[(size_t)(mB + half * 128 + r) * HH + kt + cb * 8]);
    }
  };
  auto stB = [&](int buf, int half, int kt) {
#pragma unroll
    for (int q = 0; q < 2; ++q) {
      const int r  = q * 64 + srow;
      const int cb = sc0 ^ (r & 7);
      gload16(&Bsm[buf][half][(q * 64 + w * 8) * 64],
              &W1f[(size_t)(nB + half * 128 + r) * HH + kt + cb * 8]);
    }
  };

  floatx4 acc[8][4];
#pragma unroll
  for (int i = 0; i < 8; ++i)
#pragma unroll
    for (int j = 0; j < 4; ++j) acc[i][j] = (floatx4){0.f, 0.f, 0.f, 0.f};

  // prologue: tile0 full + tile1 {B0, A0}; vmcnt(4) -> tile0 landed
  stB(0, 0, 0); stA(0, 0, 0); stA(0, 1, 0); stB(0, 1, 0);
  stB(1, 0, 64); stA(1, 0, 64);
  VMC4();
  BAR();

  f16x8 aF[2][4], b0F[2][2], b1F[2][2];
  const int bhalf  = wc >> 1;
  const int brbase = (wc & 1) * 64;

#pragma unroll 2
  for (int t = 0; t < 16; ++t) {
    const int buf = t & 1, nbuf = buf ^ 1;
    const int kt1 = (t + 1) * 64, kt2 = (t + 2) * 64;

    // ---------- phase 1 : Q(0,0) — 12 ds_read ----------
#pragma unroll
    for (int ks = 0; ks < 2; ++ks) {
#pragma unroll
      for (int i = 0; i < 4; ++i) {
        const int rl = i * 16 + l15;
        const int cb = (ks * 4 + quad) ^ (rl & 7);
        aF[ks][i] = *(const f16x8*)&Asm[buf][wr][(rl * 8 + cb) * 8];
      }
#pragma unroll
      for (int j = 0; j < 2; ++j) {
        const int rl = brbase + j * 16 + l15;
        const int cb = (ks * 4 + quad) ^ (rl & 7);
        b0F[ks][j] = *(const f16x8*)&Bsm[buf][bhalf][(rl * 8 + cb) * 8];
      }
    }
    if (t < 15) stA(nbuf, 1, kt1);
    __builtin_amdgcn_s_setprio(1);
#pragma unroll
    for (int ks = 0; ks < 2; ++ks)
#pragma unroll
      for (int i = 0; i < 4; ++i)
#pragma unroll
        for (int j = 0; j < 2; ++j)
          acc[i][j] = __builtin_amdgcn_mfma_f32_16x16x32_f16(aF[ks][i], b0F[ks][j], acc[i][j], 0, 0, 0);
    __builtin_amdgcn_s_setprio(0);
    BAR();

    // ---------- phase 2 : Q(0,1) — 4 ds_read ----------
#pragma unroll
    for (int ks = 0; ks < 2; ++ks)
#pragma unroll
      for (int j = 0; j < 2; ++j) {
        const int rl = brbase + (j + 2) * 16 + l15;
        const int cb = (ks * 4 + quad) ^ (rl & 7);
        b1F[ks][j] = *(const f16x8*)&Bsm[buf][bhalf][(rl * 8 + cb) * 8];
      }
    if (t < 15) stB(nbuf, 1, kt1);
    __builtin_amdgcn_s_setprio(1);
#pragma unroll
    for (int ks = 0; ks < 2; ++ks)
#pragma unroll
      for (int i = 0; i < 4; ++i)
#pragma unroll
        for (int j = 0; j < 2; ++j)
          acc[i][2 + j] = __builtin_amdgcn_mfma_f32_16x16x32_f16(aF[ks][i], b1F[ks][j], acc[i][2 + j], 0, 0, 0);
    __builtin_amdgcn_s_setprio(0);
    BAR();

    // ---------- phase 3 : Q(1,1) — 8 ds_read ----------
#pragma unroll
    for (int ks = 0; ks < 2; ++ks)
#pragma unroll
      for (int i = 0; i < 4; ++i) {
        const int rl = 64 + i * 16 + l15;
        const int cb = (ks * 4 + quad) ^ (rl & 7);
        aF[ks][i] = *(const f16x8*)&Asm[buf][wr][(rl * 8 + cb) * 8];
      }
    if (t < 14) stB(buf, 0, kt2);
    __builtin_amdgcn_s_setprio(1);
#pragma unroll
    for (int ks = 0; ks < 2; ++ks)
#pragma unroll
      for (int i = 0; i < 4; ++i)
#pragma unroll
        for (int j = 0; j < 2; ++j)
          acc[4 + i][2 + j] = __builtin_amdgcn_mfma_f32_16x16x32_f16(aF[ks][i], b1F[ks][j], acc[4 + i][2 + j], 0, 0, 0);
    __builtin_amdgcn_s_setprio(0);
    BAR();

    // ---------- phase 4 : Q(1,0) — regs only ----------
    if (t < 14) stA(buf, 0, kt2);
    __builtin_amdgcn_s_setprio(1);
#pragma unroll
    for (int ks = 0; ks < 2; ++ks)
#pragma unroll
      for (int i = 0; i < 4; ++i)
#pragma unroll
        for (int j = 0; j < 2; ++j)
          acc[4 + i][j] = __builtin_amdgcn_mfma_f32_16x16x32_f16(aF[ks][i], b0F[ks][j], acc[4 + i][j], 0, 0, 0);
    __builtin_amdgcn_s_setprio(0);
    if (t < 14) { VMC4(); } else { VMC0(); }
    BAR();
  }

  // ---- epilogue ----
  // stage t2 slice [32][256] -> LDS (reuse Asm; padded stride 257 = conflict-free)
  float* t2s = (float*)&Asm[0][0][0];
  {
    const int r = tid >> 4;            // 0..31
    const int c = (tid & 15) * 16;     // 0..240
#pragma unroll
    for (int q = 0; q < 4; ++q) {
      floatx4 tv = *(const floatx4*)&t2[r * HH + nB + c + q * 4];
      *(floatx4*)&t2s[r * 257 + c + q * 4] = tv;
    }
  }
  __syncthreads();

  // C/D layout col=lane&15, row=quad*4+reg. write epart[p][b][s], p = nb*4+wc
  float vv[4];
#pragma unroll
  for (int j = 0; j < 4; ++j) vv[j] = v[nB + wc * 64 + j * 16 + l15];
#pragma unroll
  for (int i = 0; i < 8; ++i) {
#pragma unroll
    for (int reg = 0; reg < 4; ++reg) {
      const int m = mB + wr * 128 + i * 16 + quad * 4 + reg;
      const int b = m & (BB - 1);
      const int s = m >> 5;
      float rs = 0.f;
#pragma unroll
      for (int j = 0; j < 4; ++j) {
        const int n = wc * 64 + j * 16 + l15;
        rs += tanh_fast(acc[i][j][reg] + t2s[b * 257 + n]) * vv[j];
      }
      rs = dpp_red16(rs);
      if (l15 == 0) epart[(size_t)(nb * 4 + wc) * MM + b * SS + s] = rs;
    }
  }
}

// ---------------- softmax over s per batch column ----------------
// epart[p][b][s] -> coalesced in s. 32 blocks x 1024 threads, 2 s per thread.
// attn written as attn[b][s].
__global__ __launch_bounds__(1024) void softmax16t(
    const float* __restrict__ epart, const int* __restrict__ masks,
    float* __restrict__ attn)
{
  const int b = blockIdx.x;
  const int tid = threadIdx.x;   // 0..1023
  __shared__ float redm[16], reds[16];
  float em[2];
  float lmax = -3e38f;
#pragma unroll
  for (int it = 0; it < 2; ++it) {
    const int s = it * 1024 + tid;
    float e = 0.f;
#pragma unroll
    for (int p = 0; p < 16; ++p) e += epart[(size_t)p * MM + b * SS + s];
    if (masks[s * BB + b] == 0) e = -1e10f;
    em[it] = e;
    lmax = fmaxf(lmax, e);
  }
#pragma unroll
  for (int off = 1; off < 64; off <<= 1) lmax = fmaxf(lmax, __shfl_xor(lmax, off));
  if ((tid & 63) == 0) redm[tid >> 6] = lmax;
  __syncthreads();
#pragma unroll
  for (int i = 0; i < 16; ++i) lmax = fmaxf(lmax, redm[i]);
  float lsum = 0.f;
#pragma unroll
  for (int it = 0; it < 2; ++it) { em[it] = __expf(em[it] - lmax); lsum += em[it]; }
#pragma unroll
  for (int off = 1; off < 64; off <<= 1) lsum += __shfl_xor(lsum, off);
  if ((tid & 63) == 0) reds[tid >> 6] = lsum;
  __syncthreads();
  float tsum = 0.f;
#pragma unroll
  for (int i = 0; i < 16; ++i) tsum += reds[i];
  const float inv = 1.0f / tsum;
#pragma unroll
  for (int it = 0; it < 2; ++it) attn[b * SS + it * 1024 + tid] = em[it] * inv;
}

// ---------------- context partials from f16 hs ----------------
__global__ __launch_bounds__(256) void context_f16t(
    const f16* __restrict__ hsf, const float* __restrict__ attn,
    float* __restrict__ ctxp)
{
  const int b  = blockIdx.x;
  const int sc = blockIdx.y;
  const int tid = threadIdx.x;
  __shared__ float sat[64];
  if (tid < 64) sat[tid] = attn[b * SS + sc * 64 + tid];
  __syncthreads();
  floatx4 acc = {0.f, 0.f, 0.f, 0.f};
#pragma unroll 4
  for (int s = 0; s < 64; ++s) {
    const float a = sat[s];
    if (a != 0.f) {   // block-uniform branch; masked rows skip the load
      f16x4 h = *(const f16x4*)&hsf[(size_t)((sc * 64 + s) * BB + b) * HH + tid * 4];
      acc.x += a * (float)h[0];
      acc.y += a * (float)h[1];
      acc.z += a * (float)h[2];
      acc.w += a * (float)h[3];
    }
  }
  *(floatx4*)&ctxp[(size_t)(sc * BB + b) * HH + tid * 4] = acc;
}

__global__ __launch_bounds__(256) void ctx_reduce32(
    const float* __restrict__ ctxp, float* __restrict__ out)
{
  const int i = blockIdx.x * 256 + threadIdx.x;
  float s = 0.f;
#pragma unroll
  for (int sc = 0; sc < 32; ++sc) s += ctxp[(size_t)sc * (BB * HH) + i];
  out[i] = s;
}

// ================= fallback path (round-2, known-passing, 3.4 MB ws) =================
__global__ __launch_bounds__(256) void t2_kernel(
    const float* __restrict__ hidden, const float* __restrict__ W2,
    const float* __restrict__ b1, const float* __restrict__ b2,
    float* __restrict__ t2)
{
  const int gw   = blockIdx.x * 4 + (threadIdx.x >> 6);
  const int n    = gw >> 5;
  const int b    = gw & 31;
  const int lane = threadIdx.x & 63;
  float acc = 0.f;
#pragma unroll
  for (int q = 0; q < 4; ++q) {
    floatx4 hv = *(const floatx4*)&hidden[b * HH + q * 256 + lane * 4];
    floatx4 wv = *(const floatx4*)&W2[(size_t)n * HH + q * 256 + lane * 4];
    acc += hv.x * wv.x + hv.y * wv.y + hv.z * wv.z + hv.w * wv.w;
  }
#pragma unroll
  for (int off = 1; off < 64; off <<= 1) acc += __shfl_xor(acc, off);
  if (lane == 0) t2[b * HH + n] = acc + b1[n] + b2[n];
}

__global__ __launch_bounds__(256) void gemm_energy_fb(
    const float* __restrict__ hs, const float* __restrict__ W1,
    const float* __restrict__ t2, const float* __restrict__ v,
    float* __restrict__ epart)
{
  const int tid = threadIdx.x;
  const int nb  = blockIdx.x;
  const int mB  = blockIdx.y * 128;
  __shared__ __align__(16) f16 Asm[128][72];
  __shared__ __align__(16) f16 Bsm[128][72];
  const int lane = tid & 63;
  const int w    = tid >> 6;
  const int quad = lane >> 4;
  const int l15  = lane & 15;
  floatx4 acc[2][8];
#pragma unroll
  for (int i = 0; i < 2; ++i)
#pragma unroll
    for (int j = 0; j < 8; ++j) acc[i][j] = (floatx4){0.f, 0.f, 0.f, 0.f};
  const int srow = tid >> 4;
  const int scol = (tid & 15) * 4;
  const float* Abase = hs + (size_t)(mB + srow) * HH + scol;
  const float* Bbase = W1 + (size_t)(nb * 128 + srow) * HH + scol;
  for (int kt = 0; kt < HH; kt += 64) {
#pragma unroll
    for (int p = 0; p < 8; ++p) {
      floatx4 fa = *(const floatx4*)(Abase + (size_t)(p * 16) * HH + kt);
      floatx4 fb = *(const floatx4*)(Bbase + (size_t)(p * 16) * HH + kt);
      f16x4 ha = {(f16)fa.x, (f16)fa.y, (f16)fa.z, (f16)fa.w};
      f16x4 hb = {(f16)fb.x, (f16)fb.y, (f16)fb.z, (f16)fb.w};
      *(f16x4*)&Asm[p * 16 + srow][scol] = ha;
      *(f16x4*)&Bsm[p * 16 + srow][scol] = hb;
    }
    __syncthreads();
#pragma unroll
    for (int ks = 0; ks < 2; ++ks) {
      f16x8 af[2], bfr[8];
#pragma unroll
      for (int i = 0; i < 2; ++i)
        af[i] = *(const f16x8*)&Asm[w * 32 + i * 16 + l15][ks * 32 + quad * 8];
#pragma unroll
      for (int j = 0; j < 8; ++j)
        bfr[j] = *(const f16x8*)&Bsm[j * 16 + l15][ks * 32 + quad * 8];
#pragma unroll
      for (int i = 0; i < 2; ++i)
#pragma unroll
        for (int j = 0; j < 8; ++j)
          acc[i][j] = __builtin_amdgcn_mfma_f32_16x16x32_f16(af[i], bfr[j], acc[i][j], 0, 0, 0);
    }
    __syncthreads();
  }
  const int nB = nb * 128;
#pragma unroll
  for (int i = 0; i < 2; ++i) {
#pragma unroll
    for (int reg = 0; reg < 4; ++reg) {
      const int m = mB + w * 32 + i * 16 + quad * 4 + reg;
      const int b = m & (BB - 1);
      float rs = 0.f;
#pragma unroll
      for (int j = 0; j < 8; ++j) {
        const int n = nB + j * 16 + l15;
        rs += tanh_fast(acc[i][j][reg] + t2[b * HH + n]) * v[n];
      }
      rs += __shfl_xor(rs, 1);
      rs += __shfl_xor(rs, 2);
      rs += __shfl_xor(rs, 4);
      rs += __shfl_xor(rs, 8);
      if (l15 == 0) epart[(size_t)nb * MM + m] = rs;
    }
  }
}

__global__ __launch_bounds__(256) void softmax8(
    const float* __restrict__ epart, const int* __restrict__ masks,
    float* __restrict__ attn)
{
  const int b = blockIdx.x;
  const int tid = threadIdx.x;
  __shared__ float redm[4], reds[4];
  float em[8];
  float lmax = -3e38f;
#pragma unroll
  for (int it = 0; it < 8; ++it) {
    const int s = it * 256 + tid;
    float e = 0.f;
#pragma unroll
    for (int p = 0; p < 8; ++p) e += epart[(size_t)p * MM + s * BB + b];
    if (masks[s * BB + b] == 0) e = -1e10f;
    em[it] = e;
    lmax = fmaxf(lmax, e);
  }
#pragma unroll
  for (int off = 1; off < 64; off <<= 1) lmax = fmaxf(lmax, __shfl_xor(lmax, off));
  if ((tid & 63) == 0) redm[tid >> 6] = lmax;
  __syncthreads();
  lmax = fmaxf(fmaxf(redm[0], redm[1]), fmaxf(redm[2], redm[3]));
  float lsum = 0.f;
#pragma unroll
  for (int it = 0; it < 8; ++it) { em[it] = __expf(em[it] - lmax); lsum += em[it]; }
#pragma unroll
  for (int off = 1; off < 64; off <<= 1) lsum += __shfl_xor(lsum, off);
  if ((tid & 63) == 0) reds[tid >> 6] = lsum;
  __syncthreads();
  const float inv = 1.0f / (reds[0] + reds[1] + reds[2] + reds[3]);
#pragma unroll
  for (int it = 0; it < 8; ++it) attn[(it * 256 + tid) * BB + b] = em[it] * inv;
}

__global__ __launch_bounds__(256) void context_fb(
    const float* __restrict__ hs, const float* __restrict__ attn,
    float* __restrict__ ctxp)
{
  const int b  = blockIdx.x;
  const int sc = blockIdx.y;
  const int tid = threadIdx.x;
  floatx4 acc = {0.f, 0.f, 0.f, 0.f};
  for (int s = sc * 256; s < sc * 256 + 256; ++s) {
    const float a = attn[s * BB + b];
    if (a != 0.f) {
      floatx4 h = *(const floatx4*)&hs[(size_t)(s * BB + b) * HH + tid * 4];
      acc.x += a * h.x; acc.y += a * h.y; acc.z += a * h.z; acc.w += a * h.w;
    }
  }
  *(floatx4*)&ctxp[(size_t)(sc * BB + b) * HH + tid * 4] = acc;
}

__global__ __launch_bounds__(256) void ctx_reduce8(
    const float* __restrict__ ctxp, float* __restrict__ out)
{
  const int i = blockIdx.x * 256 + threadIdx.x;
  float s = 0.f;
#pragma unroll
  for (int sc = 0; sc < 8; ++sc) s += ctxp[(size_t)sc * (BB * HH) + i];
  out[i] = s;
}

extern "C" void kernel_launch(void* const* d_in, const int* in_sizes, int n_in,
                              void* d_out, int out_size, void* d_ws, size_t ws_size,
                              hipStream_t stream) {
  const float* hidden = (const float*)d_in[0];  // (1,B,H)
  const float* hs     = (const float*)d_in[1];  // (S,B,H)
  const int*   masks  = (const int*)d_in[2];    // (S,B)
  const float* W1     = (const float*)d_in[3];  // (H,H)
  const float* b1     = (const float*)d_in[4];  // (H,)
  const float* W2     = (const float*)d_in[5];  // (H,H)
  const float* b2     = (const float*)d_in[6];  // (H,)
  const float* v      = (const float*)d_in[7];  // (H,)
  float* out = (float*)d_out;                   // (1,B,H)

  const size_t hsf_b   = (size_t)MM * HH * 2;    // 128 MB
  const size_t w1f_b   = (size_t)HH * HH * 2;    // 2 MB
  const size_t epart_b = (size_t)16 * MM * 4;    // 4 MB
  const size_t attn_b  = (size_t)MM * 4;         // 256 KB
  const size_t t2_b    = (size_t)BB * HH * 4;    // 128 KB
  const size_t ctxp_b  = (size_t)32 * BB * HH * 4; // 4 MB
  const size_t need = hsf_b + w1f_b + epart_b + attn_b + t2_b + ctxp_b;

  if (ws_size >= need) {
    char* p = (char*)d_ws;
    f16*   hsf   = (f16*)p;              p += hsf_b;
    f16*   W1f   = (f16*)p;              p += w1f_b;
    float* epart = (float*)p;            p += epart_b;
    float* attn  = (float*)p;            p += attn_b;
    float* t2    = (float*)p;            p += t2_b;
    float* ctxp  = (float*)p;

    prep_kernel<<<dim3(33280 + 8192), 256, 0, stream>>>(hs, W1, hidden, W2, b1, b2, hsf, W1f, t2);
    gemm_energy_8p<<<dim3(1024), 512, 0, stream>>>(hsf, W1f, t2, v, epart);
    softmax16t<<<dim3(BB), 1024, 0, stream>>>(epart, masks, attn);
    context_f16t<<<dim3(BB, 32), 256, 0, stream>>>(hsf, attn, ctxp);
    ctx_reduce32<<<dim3(BB * HH / 256), 256, 0, stream>>>(ctxp, out);
  } else {
    float* epart = (float*)d_ws;          // 8*MM
    float* attn  = epart + 8 * MM;        // MM
    float* t2    = attn + MM;             // BB*HH
    float* ctxp  = t2 + BB * HH;          // 8*BB*HH

    t2_kernel<<<dim3(BB * HH / 4), 256, 0, stream>>>(hidden, W2, b1, b2, t2);
    gemm_energy_fb<<<dim3(8, MM / 128), 256, 0, stream>>>(hs, W1, t2, v, epart);
    softmax8<<<dim3(BB), 256, 0, stream>>>(epart, masks, attn);
    context_fb<<<dim3(BB, 8), 256, 0, stream>>>(hs, attn, ctxp);
    ctx_reduce8<<<dim3(BB * HH / 256), 256, 0, stream>>>(ctxp, out);
  }
}